// Round 6
// baseline (106.419 us; speedup 1.0000x reference)
//
#include <hip/hip_runtime.h>
#include <math.h>

#define DMODEL 1024   // 16 heads x 64 dim
#define NBLK   1536   // 6 blocks/CU x 256 CU; block = 1 wave
#define BUF_F  3072   // floats per token buffer: q[1024] | k[1024] | v[1024]

typedef _Float16 f16x4 __attribute__((ext_vector_type(4)));
typedef _Float16 f16x8 __attribute__((ext_vector_type(8)));
typedef float    f32x4 __attribute__((ext_vector_type(4)));

__device__ __forceinline__ void dma16(const float* g, float* l) {
    __builtin_amdgcn_global_load_lds(
        (const __attribute__((address_space(1))) void*)g,
        (__attribute__((address_space(3))) void*)l, 16, 0, 0);
}

// Stage one token (12 KB) via 12 async DMA instrs. LDS dest is linear
// (base + lane*16B); q/k get a chunk-level XOR swizzle applied on the GLOBAL
// source address (slot s holds global chunk g with g^(row&7) == s) so the
// later MFMA-fragment ds_read_b128s are bank-conflict-free. v is linear.
__device__ __forceinline__ void stage_tok(const float* __restrict__ q,
                                          const float* __restrict__ k,
                                          const float* __restrict__ v,
                                          size_t tbase, float* buf, int lane)
{
#pragma unroll
    for (int i = 0; i < 4; ++i) {
        const int s  = 64 * i + lane;            // dest 16B slot
        const int rr = s >> 4;                   // head row
        const int oo = (s & 15) ^ (rr & 7);      // swizzled source chunk
        const int go = rr * 64 + oo * 4;         // source float offset
        dma16(q + tbase + go, buf + 256 * i);
        dma16(k + tbase + go, buf + 1024 + 256 * i);
        dma16(v + tbase + 256 * i + 4 * lane, buf + 2048 + 256 * i);
    }
}

// QK^T (mfma, S^T layout) -> causal softmax (regs) -> PV (mfma) -> 16 stores.
__device__ __forceinline__ void compute_store(float* __restrict__ out, size_t tbase,
                                              const float* buf, int r, int G)
{
    const int r7 = r & 7;
    f16x8 ka[2], qa[2];
#pragma unroll
    for (int c = 0; c < 2; ++c)
#pragma unroll
        for (int h = 0; h < 2; ++h) {
            const int slot = (8 * c + 2 * G + h) ^ r7;   // undo staging swizzle
            const f32x4 qf = *(const f32x4*)(buf +        r * 64 + 4 * slot);
            const f32x4 kf = *(const f32x4*)(buf + 1024 + r * 64 + 4 * slot);
#pragma unroll
            for (int e = 0; e < 4; ++e) {
                qa[c][4 * h + e] = (_Float16)qf[e];
                ka[c][4 * h + e] = (_Float16)kf[e];
            }
        }

    f32x4 acc = {0.f, 0.f, 0.f, 0.f};
    acc = __builtin_amdgcn_mfma_f32_16x16x32_f16(ka[0], qa[0], acc, 0, 0, 0);
    acc = __builtin_amdgcn_mfma_f32_16x16x32_f16(ka[1], qa[1], acc, 0, 0, 0);
    // lane holds S[i = r][j = 4G + e]

    float s[4];
#pragma unroll
    for (int e = 0; e < 4; ++e) {
        const int j = 4 * G + e;
        s[e] = (j > r) ? -1e30f : acc[e] * 0.125f;   // 1/sqrt(64)
    }
    float m = fmaxf(fmaxf(s[0], s[1]), fmaxf(s[2], s[3]));
    m = fmaxf(m, __shfl_xor(m, 16));
    m = fmaxf(m, __shfl_xor(m, 32));
    const float e0 = __expf(s[0] - m);
    const float e1 = __expf(s[1] - m);
    const float e2 = __expf(s[2] - m);
    const float e3 = __expf(s[3] - m);
    float sum = e0 + e1 + e2 + e3;
    sum += __shfl_xor(sum, 16);
    sum += __shfl_xor(sum, 32);
    const float inv = 1.0f / sum;
    f16x4 pa;
    pa[0] = (_Float16)(e0 * inv);
    pa[1] = (_Float16)(e1 * inv);
    pa[2] = (_Float16)(e2 * inv);
    pa[3] = (_Float16)(e3 * inv);

    // v fragments from LDS: vb[t] = V[4G+t][16cg + r]
    const float* vb = buf + 2048;
#pragma unroll
    for (int cg = 0; cg < 4; ++cg) {
        f16x4 vf;
#pragma unroll
        for (int t_ = 0; t_ < 4; ++t_)
            vf[t_] = (_Float16)vb[(4 * G + t_) * 64 + 16 * cg + r];
        f32x4 o = {0.f, 0.f, 0.f, 0.f};
        o = __builtin_amdgcn_mfma_f32_16x16x16f16(pa, vf, o, 0, 0, 0);
        float* obase = out + tbase + (size_t)(4 * G) * 64 + 16 * cg + r;
#pragma unroll
        for (int e = 0; e < 4; ++e)
            obase[e * 64] = o[e];   // 16 scalar stores total per token
    }
}

__global__ __launch_bounds__(64) void temporal_attn_kernel(
    const float* __restrict__ q,
    const float* __restrict__ k,
    const float* __restrict__ v,
    float* __restrict__ out, int ntok)
{
    __shared__ float smem[2 * BUF_F];   // 24 KB: double-buffered token stage
    const int lane = threadIdx.x;       // block = exactly 1 wave
    const int r = lane & 15;
    const int G = lane >> 4;
    const int S = NBLK;                 // token grid-stride
    int t = blockIdx.x;
    if (t >= ntok) return;

    // Prologue: fill both buffers, wait only for the first (12 = DMA(t1) in flight).
    stage_tok(q, k, v, (size_t)t * DMODEL, smem, lane);
    if (t + S < ntok)
        stage_tok(q, k, v, (size_t)(t + S) * DMODEL, smem + BUF_F, lane);
    asm volatile("s_waitcnt vmcnt(12)" ::: "memory");
    __builtin_amdgcn_sched_barrier(0);

    int cur = 0;
    for (; t < ntok; t += S) {
        float* buf = (float*)smem + cur * BUF_F;
        compute_store(out, (size_t)t * DMODEL, buf, r, G);
        __builtin_amdgcn_sched_barrier(0);
        if (t + 2 * S < ntok) {
            // refill the buffer just consumed; its ds_reads are already drained
            // (stores depend on their data).
            stage_tok(q, k, v, (size_t)(t + 2 * S) * DMODEL, buf, lane);
            __builtin_amdgcn_sched_barrier(0);
            // younger-than-DMA(t+1): 16 stores(t) + 12 DMA(t+2) = 28. Never 0:
            // next tile's loads stay in flight across the wait.
            asm volatile("s_waitcnt vmcnt(28)" ::: "memory");
        } else if (t + S < ntok) {
            asm volatile("s_waitcnt vmcnt(16)" ::: "memory");   // only stores(t) younger
        }
        __builtin_amdgcn_sched_barrier(0);
        cur ^= 1;
    }
}

extern "C" void kernel_launch(void* const* d_in, const int* in_sizes, int n_in,
                              void* d_out, int out_size, void* d_ws, size_t ws_size,
                              hipStream_t stream) {
    const float* q = (const float*)d_in[0];
    const float* k = (const float*)d_in[1];
    const float* v = (const float*)d_in[2];
    float* o = (float*)d_out;
    const int ntok = in_sizes[0] / DMODEL;   // B*S = 32768
    temporal_attn_kernel<<<NBLK, 64, 0, stream>>>(q, k, v, o, ntok);
}

// Round 8
// 95.696 us; speedup vs baseline: 1.1121x; 1.1121x over previous
//
#include <hip/hip_runtime.h>
#include <math.h>

#define NHEADS 16
#define HD 64
#define DMODEL 1024          // NHEADS * HD
#define QK_PAD 68            // row stride in floats (64 + 4 pad) -> 2-way banks, free

typedef float f32x4 __attribute__((ext_vector_type(4)));

__global__ __launch_bounds__(256) void temporal_attn_kernel(
    const float* __restrict__ q,
    const float* __restrict__ k,
    const float* __restrict__ v,
    float* __restrict__ out)
{
    __shared__ float  qs[NHEADS * QK_PAD];
    __shared__ float  ks[NHEADS * QK_PAD];
    __shared__ float4 vs[NHEADS * (HD / 4)];   // unpadded: b128 reads are 2-way (free)
    __shared__ float  ps[NHEADS][NHEADS + 1];

    const int t = threadIdx.x;
    const size_t base = (size_t)blockIdx.x * DMODEL;
    const int r = t >> 4;   // row   0..15
    const int c = t & 15;   // col/4 0..15

    // ---- stage token tiles: fully coalesced, 16B/lane ----
    const float4 qv = ((const float4*)(q + base))[t];
    const float4 kv = ((const float4*)(k + base))[t];
    const float4 vv = ((const float4*)(v + base))[t];
    *((float4*)&qs[r * QK_PAD + 4 * c]) = qv;
    *((float4*)&ks[r * QK_PAD + 4 * c]) = kv;
    vs[t] = vv;
    __syncthreads();

    // ---- scores: thread t owns s[i=r][j=c] = (q_row_r . k_row_c) / 8 ----
    const float4* qi = (const float4*)&qs[r * QK_PAD];
    const float4* kj = (const float4*)&ks[c * QK_PAD];
    float acc = 0.f;
    #pragma unroll
    for (int d = 0; d < HD / 4; ++d) {
        const float4 a = qi[d];
        const float4 b = kj[d];
        acc = fmaf(a.x, b.x, acc);
        acc = fmaf(a.y, b.y, acc);
        acc = fmaf(a.z, b.z, acc);
        acc = fmaf(a.w, b.w, acc);
    }
    acc *= 0.125f;                 // 1/sqrt(64)
    if (c > r) acc = -1e30f;       // causal over heads

    // ---- softmax over j within each 16-lane row group ----
    float m = acc;
    #pragma unroll
    for (int mask = 8; mask >= 1; mask >>= 1)
        m = fmaxf(m, __shfl_xor(m, mask, 16));
    const float p = __expf(acc - m);   // masked lanes: exp(-huge) == 0
    float s = p;
    #pragma unroll
    for (int mask = 8; mask >= 1; mask >>= 1)
        s += __shfl_xor(s, mask, 16);
    ps[r][c] = p / s;
    __syncthreads();

    // ---- PV: out[i=r][4c..4c+3] = sum_j p[i][j] * v[j][4c..4c+3] ----
    float4 o = make_float4(0.f, 0.f, 0.f, 0.f);
    #pragma unroll
    for (int j = 0; j < NHEADS; ++j) {
        const float  pij = ps[r][j];
        const float4 vj  = vs[j * (HD / 4) + c];
        o.x = fmaf(pij, vj.x, o.x);
        o.y = fmaf(pij, vj.y, o.y);
        o.z = fmaf(pij, vj.z, o.z);
        o.w = fmaf(pij, vj.w, o.w);
    }
    // Full-line nontemporal store: 64 lanes x 16B contiguous = complete 64B
    // lines -> write-around, keeping L2/L3 capacity for the input streams.
    // (clang requires an ext_vector pointer, not HIP's struct float4.)
    f32x4 ov;
    ov.x = o.x; ov.y = o.y; ov.z = o.z; ov.w = o.w;
    __builtin_nontemporal_store(ov, ((f32x4*)(out + base)) + t);
}

extern "C" void kernel_launch(void* const* d_in, const int* in_sizes, int n_in,
                              void* d_out, int out_size, void* d_ws, size_t ws_size,
                              hipStream_t stream) {
    const float* q = (const float*)d_in[0];
    const float* k = (const float*)d_in[1];
    const float* v = (const float*)d_in[2];
    float* o = (float*)d_out;
    const int ntok = in_sizes[0] / DMODEL;   // B*S tokens, one block each
    temporal_attn_kernel<<<ntok, 256, 0, stream>>>(q, k, v, o);
}